// Round 8
// baseline (120.002 us; speedup 1.0000x reference)
//
#include <hip/hip_runtime.h>
#include <hip/hip_bf16.h>

// LRGCN_Batch — reference returns ONLY h2, so the _relation() path is dead.
// Live math, REASSOCIATED ((A·x)@W == A·(x@W), A = weighted-mean gather op):
//   K1: Y1 = x @ W1                      (bf16 MFMA, fp32 acc, bf16 store)
//   K2: Y2 = elu(gather_mean(Y1)) @ W2   (FUSED: gather->LDS tile->MFMA)
//   K3: out = gather_mean(Y2)            (fp32 out)
// R8: temporal PHASE-BUCKETING of the gathers. Neighbors are processed in
// idx-range passes (K2: 4 passes x 12500 rows = 3.2MB working set/pass;
// K3: 2 passes x 3.2MB) so each XCD's 4MiB L2 can hold the whole live range
// -> L2-miss (L3-service @ ~3TB/s, the measured R3 bottleneck) drops.
// Granule stays 16B/lane, 256B/node (R6 lesson: never shrink below 128B).
// Loads batched 16-deep, exec-mask predicated -> MLP + request count kept.
// Per-node sum order is bucket-grouped (fp32 reassoc only, ~1e-7 effect).

#define NN   50000
#define KNBR 16
#define NF   128   // NFEAT == NHID
#define NC   64    // NCLASS

typedef short s16x8 __attribute__((ext_vector_type(8)));  // 8 bf16 (4 VGPR)
typedef float f32x4 __attribute__((ext_vector_type(4)));

static __device__ __forceinline__ unsigned short f2bf(float f) {
  __hip_bfloat16 h = __float2bfloat16(f);  // RNE
  return reinterpret_cast<unsigned short&>(h);
}
static __device__ __forceinline__ float bflo(unsigned int u) {
  return __uint_as_float(u << 16);
}
static __device__ __forceinline__ float bfhi(unsigned int u) {
  return __uint_as_float(u & 0xffff0000u);
}

// ---------------- K1: C_bf16[M x 128] = A_f32[M x 128] @ B_f32[128 x 128] --
// m89-verified MFMA fragment layouts; row-major bf16 C.
__global__ __launch_bounds__(256, 2) void gemm_mfma_128(
    const float* __restrict__ A, const float* __restrict__ B,
    unsigned short* __restrict__ C, int M) {
  constexpr int CT = 8;
  constexpr int KP = 136;       // LDS row stride in bf16 (272B: 16B-aligned)
  __shared__ unsigned short Wt_s[128 * KP];
  __shared__ unsigned short st_s[4][16 * KP];

  const int t = threadIdx.x;
  for (int i = t; i < 128 * 128; i += 256) {   // stage W^T as bf16
    const int k = i >> 7, c = i & 127;
    Wt_s[c * KP + k] = f2bf(B[i]);
  }
  __syncthreads();

  const int w   = t >> 6;
  const int l   = t & 63;
  const int lr  = l & 15;
  const int lk  = l >> 4;
  const int bm0 = blockIdx.x * 128 + w * 32;

  const int row0 = bm0 + lr, row1 = row0 + 16;
  const int r0c = row0 < M ? row0 : M - 1;
  const int r1c = row1 < M ? row1 : M - 1;

  f32x4 acc[2][CT];
#pragma unroll
  for (int mt = 0; mt < 2; ++mt)
#pragma unroll
    for (int ct = 0; ct < CT; ++ct) acc[mt][ct] = (f32x4){0.f, 0.f, 0.f, 0.f};

  const float4* A4 = reinterpret_cast<const float4*>(A);
#pragma unroll
  for (int ks = 0; ks < 4; ++ks) {
    const float4 u0 = A4[(size_t)r0c * 32 + ks * 8 + lk * 2];
    const float4 u1 = A4[(size_t)r0c * 32 + ks * 8 + lk * 2 + 1];
    const float4 v0 = A4[(size_t)r1c * 32 + ks * 8 + lk * 2];
    const float4 v1 = A4[(size_t)r1c * 32 + ks * 8 + lk * 2 + 1];
    unsigned short a0[8] = {f2bf(u0.x), f2bf(u0.y), f2bf(u0.z), f2bf(u0.w),
                            f2bf(u1.x), f2bf(u1.y), f2bf(u1.z), f2bf(u1.w)};
    unsigned short a1[8] = {f2bf(v0.x), f2bf(v0.y), f2bf(v0.z), f2bf(v0.w),
                            f2bf(v1.x), f2bf(v1.y), f2bf(v1.z), f2bf(v1.w)};
    s16x8 af0 = __builtin_bit_cast(s16x8, *(uint4*)a0);
    s16x8 af1 = __builtin_bit_cast(s16x8, *(uint4*)a1);
    const int kb = ks * 32 + lk * 8;
#pragma unroll
    for (int ct = 0; ct < CT; ++ct) {
      const uint4 bw = *reinterpret_cast<const uint4*>(&Wt_s[(ct * 16 + lr) * KP + kb]);
      const s16x8 bf = __builtin_bit_cast(s16x8, bw);
      acc[0][ct] = __builtin_amdgcn_mfma_f32_16x16x32_bf16(af0, bf, acc[0][ct], 0, 0, 0);
      acc[1][ct] = __builtin_amdgcn_mfma_f32_16x16x32_bf16(af1, bf, acc[1][ct], 0, 0, 0);
    }
  }

  unsigned short* st = st_s[w];
#pragma unroll
  for (int mt = 0; mt < 2; ++mt) {
#pragma unroll
    for (int ct = 0; ct < CT; ++ct)
#pragma unroll
      for (int r = 0; r < 4; ++r)
        st[(lk * 4 + r) * KP + ct * 16 + lr] = f2bf(acc[mt][ct][r]);
    // wave-internal LDS readback (same wave wrote it)
#pragma unroll
    for (int p = 0; p < 4; ++p) {
      const int ri = p * 4 + lk;
      const int grow = bm0 + mt * 16 + ri;
      if (grow < M) {
        const uint4 v = *reinterpret_cast<const uint4*>(&st[ri * KP + lr * 8]);
        *reinterpret_cast<uint4*>(&C[(size_t)grow * NF + lr * 8]) = v;
      }
    }
  }
}

// ---------------- K2: FUSED gather1(4-pass) + elu + GEMM2 -------------------
// 512 threads, 64 nodes/block. Gather thread = (node-group t>>4 of 16 lanes,
// lane l = t&15 covering 16B of the 256B row). Each thread handles nodes
// na = t>>4 and nb = 32 + na, both inside each idx-range pass.
__global__ __launch_bounds__(512, 4) void gather_gemm_fused(
    const unsigned short* __restrict__ Y1, const int* __restrict__ idx,
    const float* __restrict__ w, const float* __restrict__ W2,
    unsigned short* __restrict__ Y2) {
  constexpr int KP = 136;
  __shared__ int   idx_s[64][KNBR];
  __shared__ float w_s[64][KNBR];
  __shared__ unsigned short Wt_s[64 * KP];   // W2^T: [c][k]
  __shared__ unsigned short h1_s[64 * KP];   // h1 tile: [n][f]
  __shared__ unsigned short st_s[8][16 * 40];

  const int t  = threadIdx.x;
  const int n0 = blockIdx.x * 64;

#pragma unroll
  for (int j = 0; j < 2; ++j) {              // 1024 (idx,w) pairs
    const int i = t + j * 512;
    const int node = i >> 4, k = i & 15;
    int gn = n0 + node; if (gn >= NN) gn = NN - 1;
    const int g = gn * (KNBR + 1) + 1 + k;
    idx_s[node][k] = __builtin_nontemporal_load(&idx[g]);
    w_s[node][k]   = __builtin_nontemporal_load(&w[g]);
  }
#pragma unroll
  for (int j = 0; j < 16; ++j) {             // W2 [128][64] -> Wt_s bf16
    const int i = t + j * 512;
    const int k = i >> 6, c = i & 63;
    Wt_s[c * KP + k] = f2bf(W2[i]);
  }
  __syncthreads();

  const uint4* Y14 = reinterpret_cast<const uint4*>(Y1);  // row = 16 uint4
  {
    const int l  = t & 15;
    const int na = t >> 4;        // 0..31
    const int nb = 32 + na;
    float accA[8], accB[8];
#pragma unroll
    for (int j = 0; j < 8; ++j) { accA[j] = 0.f; accB[j] = 0.f; }

    for (int pass = 0; pass < 4; ++pass) {
      const unsigned lo = (unsigned)(pass * 12500);
      uint4 v[KNBR];
      unsigned mk;
      // ---- node A: predicated batched loads, then masked accumulate ----
      mk = 0;
#pragma unroll
      for (int k = 0; k < KNBR; ++k) {
        const unsigned id = (unsigned)idx_s[na][k];
        if (id - lo < 12500u) {
          v[k] = Y14[(size_t)id * 16 + l];
          mk |= 1u << k;
        }
      }
#pragma unroll
      for (int k = 0; k < KNBR; ++k) {
        if (mk & (1u << k)) {
          const float wv = w_s[na][k];
          accA[0] += wv * bflo(v[k].x); accA[1] += wv * bfhi(v[k].x);
          accA[2] += wv * bflo(v[k].y); accA[3] += wv * bfhi(v[k].y);
          accA[4] += wv * bflo(v[k].z); accA[5] += wv * bfhi(v[k].z);
          accA[6] += wv * bflo(v[k].w); accA[7] += wv * bfhi(v[k].w);
        }
      }
      // ---- node B ----
      mk = 0;
#pragma unroll
      for (int k = 0; k < KNBR; ++k) {
        const unsigned id = (unsigned)idx_s[nb][k];
        if (id - lo < 12500u) {
          v[k] = Y14[(size_t)id * 16 + l];
          mk |= 1u << k;
        }
      }
#pragma unroll
      for (int k = 0; k < KNBR; ++k) {
        if (mk & (1u << k)) {
          const float wv = w_s[nb][k];
          accB[0] += wv * bflo(v[k].x); accB[1] += wv * bfhi(v[k].x);
          accB[2] += wv * bflo(v[k].y); accB[3] += wv * bfhi(v[k].y);
          accB[4] += wv * bflo(v[k].z); accB[5] += wv * bfhi(v[k].z);
          accB[6] += wv * bflo(v[k].w); accB[7] += wv * bfhi(v[k].w);
        }
      }
      __syncthreads();   // keep the block's waves phase-aligned
    }

#pragma unroll
    for (int half = 0; half < 2; ++half) {
      const float* ac = half ? accB : accA;
      const int    n  = half ? nb : na;
      uint4 r;
      unsigned int* rp = &r.x;
#pragma unroll
      for (int j = 0; j < 4; ++j) {
        float a = ac[2 * j] * (1.f / KNBR);
        float b = ac[2 * j + 1] * (1.f / KNBR);
        a = a > 0.f ? a : expm1f(a);  // jax.nn.elu
        b = b > 0.f ? b : expm1f(b);
        rp[j] = (unsigned int)f2bf(a) | ((unsigned int)f2bf(b) << 16);
      }
      *reinterpret_cast<uint4*>(&h1_s[n * KP + l * 8]) = r;
    }
  }
  __syncthreads();

  {  // MFMA: h1_s[64x128] @ Wt_s -> 64x64
    const int wv_ = t >> 6;        // wave 0..7
    const int l   = t & 63;
    const int lr  = l & 15;
    const int lk  = l >> 4;
    const int mt  = wv_ >> 1;      // row tile (16 rows)
    const int ch  = wv_ & 1;       // col half (32 cols)

    f32x4 acc[2];
    acc[0] = (f32x4){0.f, 0.f, 0.f, 0.f};
    acc[1] = (f32x4){0.f, 0.f, 0.f, 0.f};
#pragma unroll
    for (int ks = 0; ks < 4; ++ks) {
      const int kb = ks * 32 + lk * 8;
      const uint4 aw = *reinterpret_cast<const uint4*>(&h1_s[(mt * 16 + lr) * KP + kb]);
      const s16x8 af = __builtin_bit_cast(s16x8, aw);
#pragma unroll
      for (int ct = 0; ct < 2; ++ct) {
        const uint4 bw = *reinterpret_cast<const uint4*>(
            &Wt_s[(ch * 32 + ct * 16 + lr) * KP + kb]);
        const s16x8 bf = __builtin_bit_cast(s16x8, bw);
        acc[ct] = __builtin_amdgcn_mfma_f32_16x16x32_bf16(af, bf, acc[ct], 0, 0, 0);
      }
    }

    unsigned short* st = st_s[wv_];
#pragma unroll
    for (int ct = 0; ct < 2; ++ct)
#pragma unroll
      for (int r = 0; r < 4; ++r)
        st[(lk * 4 + r) * 40 + ct * 16 + lr] = f2bf(acc[ct][r]);
    // wave-internal readback, transposed
    const int ri = l >> 2;
    const int grow = n0 + mt * 16 + ri;
    if (grow < NN) {
      const uint4 v = *reinterpret_cast<const uint4*>(&st[ri * 40 + (l & 3) * 8]);
      *reinterpret_cast<uint4*>(&Y2[(size_t)grow * NC + ch * 32 + (l & 3) * 8]) = v;
    }
  }
}

// ---------------- K3: gather-mean(2-pass) over Y2 [NN][64] bf16 -> fp32 out -
// 512 threads, 64 nodes/block; thread = (n = t>>3, l = t&7): 16B granule,
// 8 lanes cover the 128B row.
__global__ __launch_bounds__(512, 4) void gather_mean_out(
    const unsigned short* __restrict__ Y2, const int* __restrict__ idx,
    const float* __restrict__ w, float* __restrict__ out) {
  __shared__ int   idx_s[64][KNBR];
  __shared__ float w_s[64][KNBR];
  const int t  = threadIdx.x;
  const int n0 = blockIdx.x * 64;
#pragma unroll
  for (int j = 0; j < 2; ++j) {
    const int i = t + j * 512;
    const int node = i >> 4, k = i & 15;
    int gn = n0 + node; if (gn >= NN) gn = NN - 1;
    const int g = gn * (KNBR + 1) + 1 + k;
    idx_s[node][k] = __builtin_nontemporal_load(&idx[g]);
    w_s[node][k]   = __builtin_nontemporal_load(&w[g]);
  }
  __syncthreads();

  const int n = t >> 3, l = t & 7;
  const int gn = n0 + n;
  const bool valid = gn < NN;           // no early return: barriers below
  const uint4* Y24 = reinterpret_cast<const uint4*>(Y2);  // row = 8 uint4
  float acc[8];
#pragma unroll
  for (int j = 0; j < 8; ++j) acc[j] = 0.f;

  for (int pass = 0; pass < 2; ++pass) {
    const unsigned lo = (unsigned)(pass * 25000);
    uint4 v[KNBR];
    unsigned mk = 0;
#pragma unroll
    for (int k = 0; k < KNBR; ++k) {
      const unsigned id = (unsigned)idx_s[n][k];
      if (id - lo < 25000u) {
        v[k] = Y24[(size_t)id * 8 + l];
        mk |= 1u << k;
      }
    }
#pragma unroll
    for (int k = 0; k < KNBR; ++k) {
      if (mk & (1u << k)) {
        const float wv = w_s[n][k];
        acc[0] += wv * bflo(v[k].x); acc[1] += wv * bfhi(v[k].x);
        acc[2] += wv * bflo(v[k].y); acc[3] += wv * bfhi(v[k].y);
        acc[4] += wv * bflo(v[k].z); acc[5] += wv * bfhi(v[k].z);
        acc[6] += wv * bflo(v[k].w); acc[7] += wv * bfhi(v[k].w);
      }
    }
    __syncthreads();   // phase alignment
  }

  if (valid) {
    float4* o4 = reinterpret_cast<float4*>(out);
    const size_t ob = ((size_t)gn * NC + l * 8) >> 2;
    o4[ob] = make_float4(acc[0] * (1.f / KNBR), acc[1] * (1.f / KNBR),
                         acc[2] * (1.f / KNBR), acc[3] * (1.f / KNBR));
    o4[ob + 1] = make_float4(acc[4] * (1.f / KNBR), acc[5] * (1.f / KNBR),
                             acc[6] * (1.f / KNBR), acc[7] * (1.f / KNBR));
  }
}

extern "C" void kernel_launch(void* const* d_in, const int* in_sizes, int n_in,
                              void* d_out, int out_size, void* d_ws,
                              size_t ws_size, hipStream_t stream) {
  // 0:x 1:adj1_idx 2:adj1_w1(dead) 3:adj1_w2 4:adj2_idx 5:adj2_w1(dead)
  // 6:adj2_w2 7:W1 8:W2 9..18: relation params (ALL dead)
  const float* x   = (const float*)d_in[0];
  const int*   a1i = (const int*)d_in[1];
  const float* a1w = (const float*)d_in[3];
  const int*   a2i = (const int*)d_in[4];
  const float* a2w = (const float*)d_in[6];
  const float* W1  = (const float*)d_in[7];
  const float* W2  = (const float*)d_in[8];
  float*       out = (float*)d_out;

  unsigned short* Y1 = (unsigned short*)d_ws;    // [NN][128] bf16, 12.8 MB
  unsigned short* Y2 = Y1 + (size_t)NN * NF;     // [NN][64]  bf16,  6.4 MB

  gemm_mfma_128<<<(NN + 127) / 128, 256, 0, stream>>>(x, W1, Y1, NN);
  gather_gemm_fused<<<(NN + 63) / 64, 512, 0, stream>>>(Y1, a1i, a1w, W2, Y2);
  gather_mean_out<<<(NN + 63) / 64, 512, 0, stream>>>(Y2, a2i, a2w, out);
}

// Round 9
// 57.860 us; speedup vs baseline: 2.0740x; 2.0740x over previous
//
#include <hip/hip_runtime.h>
#include <hip/hip_bf16.h>

// LRGCN_Batch — reference returns ONLY h2, so the _relation() path is dead.
// Live math, REASSOCIATED ((A·x)@W == A·(x@W), A = weighted-mean gather op):
//   K1: Y1 = x @ W1                      (bf16 MFMA, fp32 acc, bf16 store)
//   K2: Y2 = elu(gather_mean(Y1)) @ W2   (FUSED: gather->LDS tile->MFMA)
//   K3: out = gather_mean(Y2)            (fp32 out)
// R9: revert R8's phase-bucketing (predicated loads broke the 16-deep batch,
// +barriers, +bank conflicts: 58.7->120us despite FETCH 87->65MB; the
// remaining FETCH is COMPULSORY per-XCD traffic ~ NXCD x buffer, immune to
// temporal chunking). Back to R7 (58.7us) + one safe change: K2 stages W2
// into LDS AFTER the gather phase, so the pre-gather critical path is just
// the idx/w staging; W2 staging hides in other waves' gather latency.
// Gathers are at the ~3.3TB/s beyond-L2 service floor (R3/R6/R8 evidence).
// Arithmetic identical to R7 -> absmax 2.44e-4.

#define NN   50000
#define KNBR 16
#define NF   128   // NFEAT == NHID
#define NC   64    // NCLASS

typedef short s16x8 __attribute__((ext_vector_type(8)));  // 8 bf16 (4 VGPR)
typedef float f32x4 __attribute__((ext_vector_type(4)));

static __device__ __forceinline__ unsigned short f2bf(float f) {
  __hip_bfloat16 h = __float2bfloat16(f);  // RNE
  return reinterpret_cast<unsigned short&>(h);
}
static __device__ __forceinline__ float bflo(unsigned int u) {
  return __uint_as_float(u << 16);
}
static __device__ __forceinline__ float bfhi(unsigned int u) {
  return __uint_as_float(u & 0xffff0000u);
}

// ---------------- K1: C_bf16[M x 128] = A_f32[M x 128] @ B_f32[128 x 128] --
// m89-verified MFMA fragment layouts; row-major bf16 C.
__global__ __launch_bounds__(256, 2) void gemm_mfma_128(
    const float* __restrict__ A, const float* __restrict__ B,
    unsigned short* __restrict__ C, int M) {
  constexpr int CT = 8;
  constexpr int KP = 136;       // LDS row stride in bf16 (272B: 16B-aligned)
  __shared__ unsigned short Wt_s[128 * KP];
  __shared__ unsigned short st_s[4][16 * KP];

  const int t = threadIdx.x;
  for (int i = t; i < 128 * 128; i += 256) {   // stage W^T as bf16
    const int k = i >> 7, c = i & 127;
    Wt_s[c * KP + k] = f2bf(B[i]);
  }
  __syncthreads();

  const int w   = t >> 6;
  const int l   = t & 63;
  const int lr  = l & 15;
  const int lk  = l >> 4;
  const int bm0 = blockIdx.x * 128 + w * 32;

  const int row0 = bm0 + lr, row1 = row0 + 16;
  const int r0c = row0 < M ? row0 : M - 1;
  const int r1c = row1 < M ? row1 : M - 1;

  f32x4 acc[2][CT];
#pragma unroll
  for (int mt = 0; mt < 2; ++mt)
#pragma unroll
    for (int ct = 0; ct < CT; ++ct) acc[mt][ct] = (f32x4){0.f, 0.f, 0.f, 0.f};

  const float4* A4 = reinterpret_cast<const float4*>(A);
#pragma unroll
  for (int ks = 0; ks < 4; ++ks) {
    const float4 u0 = A4[(size_t)r0c * 32 + ks * 8 + lk * 2];
    const float4 u1 = A4[(size_t)r0c * 32 + ks * 8 + lk * 2 + 1];
    const float4 v0 = A4[(size_t)r1c * 32 + ks * 8 + lk * 2];
    const float4 v1 = A4[(size_t)r1c * 32 + ks * 8 + lk * 2 + 1];
    unsigned short a0[8] = {f2bf(u0.x), f2bf(u0.y), f2bf(u0.z), f2bf(u0.w),
                            f2bf(u1.x), f2bf(u1.y), f2bf(u1.z), f2bf(u1.w)};
    unsigned short a1[8] = {f2bf(v0.x), f2bf(v0.y), f2bf(v0.z), f2bf(v0.w),
                            f2bf(v1.x), f2bf(v1.y), f2bf(v1.z), f2bf(v1.w)};
    s16x8 af0 = __builtin_bit_cast(s16x8, *(uint4*)a0);
    s16x8 af1 = __builtin_bit_cast(s16x8, *(uint4*)a1);
    const int kb = ks * 32 + lk * 8;
#pragma unroll
    for (int ct = 0; ct < CT; ++ct) {
      const uint4 bw = *reinterpret_cast<const uint4*>(&Wt_s[(ct * 16 + lr) * KP + kb]);
      const s16x8 bf = __builtin_bit_cast(s16x8, bw);
      acc[0][ct] = __builtin_amdgcn_mfma_f32_16x16x32_bf16(af0, bf, acc[0][ct], 0, 0, 0);
      acc[1][ct] = __builtin_amdgcn_mfma_f32_16x16x32_bf16(af1, bf, acc[1][ct], 0, 0, 0);
    }
  }

  unsigned short* st = st_s[w];
#pragma unroll
  for (int mt = 0; mt < 2; ++mt) {
#pragma unroll
    for (int ct = 0; ct < CT; ++ct)
#pragma unroll
      for (int r = 0; r < 4; ++r)
        st[(lk * 4 + r) * KP + ct * 16 + lr] = f2bf(acc[mt][ct][r]);
    // wave-internal LDS readback (same wave wrote it)
#pragma unroll
    for (int p = 0; p < 4; ++p) {
      const int ri = p * 4 + lk;
      const int grow = bm0 + mt * 16 + ri;
      if (grow < M) {
        const uint4 v = *reinterpret_cast<const uint4*>(&st[ri * KP + lr * 8]);
        *reinterpret_cast<uint4*>(&C[(size_t)grow * NF + lr * 8]) = v;
      }
    }
  }
}

// ---------------- K2: FUSED gather1 + elu + GEMM2 ---------------------------
// 512 threads, 64 nodes/block.
//  A: stage idx/w (1024 pairs) ONLY, barrier.        <- short critical path
//  B: gather: thread=(n = half*32 + t>>4, l = t&15); v[16] batched uint4
//     loads of Y1 (16B granule, 16 lanes cover the 256B row -> coalesced);
//     weighted mean, elu, bf16 -> h1_s[n][l*8..] (stride KP).
//  C: stage W2^T bf16 (overlaps other waves' gather latency), barrier.
//  D: MFMA: wave w: mt=w>>1 (16 rows), ch=w&1 (32 cols): 4 ks x 2 ct.
//  E: per-wave LDS transpose -> coalesced uint4 stores to Y2 [NN][64] bf16.
__global__ __launch_bounds__(512, 4) void gather_gemm_fused(
    const unsigned short* __restrict__ Y1, const int* __restrict__ idx,
    const float* __restrict__ w, const float* __restrict__ W2,
    unsigned short* __restrict__ Y2) {
  constexpr int KP = 136;
  __shared__ int   idx_s[64][KNBR];
  __shared__ float w_s[64][KNBR];
  __shared__ unsigned short Wt_s[64 * KP];   // W2^T: [c][k]
  __shared__ unsigned short h1_s[64 * KP];   // h1 tile: [n][f]
  __shared__ unsigned short st_s[8][16 * 40];

  const int t  = threadIdx.x;
  const int n0 = blockIdx.x * 64;

#pragma unroll
  for (int j = 0; j < 2; ++j) {              // 1024 (idx,w) pairs
    const int i = t + j * 512;
    const int node = i >> 4, k = i & 15;
    int gn = n0 + node; if (gn >= NN) gn = NN - 1;
    const int g = gn * (KNBR + 1) + 1 + k;
    idx_s[node][k] = idx[g];
    w_s[node][k]   = w[g];
  }
  __syncthreads();

  const uint4* Y14 = reinterpret_cast<const uint4*>(Y1);  // row = 16 uint4
  {
    const int l = t & 15;
#pragma unroll
    for (int half = 0; half < 2; ++half) {
      const int n = half * 32 + (t >> 4);
      uint4 v[KNBR];
#pragma unroll
      for (int k = 0; k < KNBR; ++k)
        v[k] = Y14[(size_t)idx_s[n][k] * 16 + l];
      float acc[8];
#pragma unroll
      for (int j = 0; j < 8; ++j) acc[j] = 0.f;
#pragma unroll
      for (int k = 0; k < KNBR; ++k) {
        const float wv = w_s[n][k];
        acc[0] += wv * bflo(v[k].x); acc[1] += wv * bfhi(v[k].x);
        acc[2] += wv * bflo(v[k].y); acc[3] += wv * bfhi(v[k].y);
        acc[4] += wv * bflo(v[k].z); acc[5] += wv * bfhi(v[k].z);
        acc[6] += wv * bflo(v[k].w); acc[7] += wv * bfhi(v[k].w);
      }
      uint4 r;
      unsigned int* rp = &r.x;
#pragma unroll
      for (int j = 0; j < 4; ++j) {
        float a = acc[2 * j] * (1.f / KNBR);
        float b = acc[2 * j + 1] * (1.f / KNBR);
        a = a > 0.f ? a : expm1f(a);  // jax.nn.elu
        b = b > 0.f ? b : expm1f(b);
        rp[j] = (unsigned int)f2bf(a) | ((unsigned int)f2bf(b) << 16);
      }
      *reinterpret_cast<uint4*>(&h1_s[n * KP + l * 8]) = r;
    }
  }

#pragma unroll
  for (int j = 0; j < 16; ++j) {             // W2 [128][64] -> Wt_s bf16
    const int i = t + j * 512;
    const int k = i >> 6, c = i & 63;
    Wt_s[c * KP + k] = f2bf(W2[i]);
  }
  __syncthreads();

  {  // MFMA: h1_s[64x128] @ Wt_s -> 64x64
    const int wv_ = t >> 6;        // wave 0..7
    const int l   = t & 63;
    const int lr  = l & 15;
    const int lk  = l >> 4;
    const int mt  = wv_ >> 1;      // row tile (16 rows)
    const int ch  = wv_ & 1;       // col half (32 cols)

    f32x4 acc[2];
    acc[0] = (f32x4){0.f, 0.f, 0.f, 0.f};
    acc[1] = (f32x4){0.f, 0.f, 0.f, 0.f};
#pragma unroll
    for (int ks = 0; ks < 4; ++ks) {
      const int kb = ks * 32 + lk * 8;
      const uint4 aw = *reinterpret_cast<const uint4*>(&h1_s[(mt * 16 + lr) * KP + kb]);
      const s16x8 af = __builtin_bit_cast(s16x8, aw);
#pragma unroll
      for (int ct = 0; ct < 2; ++ct) {
        const uint4 bw = *reinterpret_cast<const uint4*>(
            &Wt_s[(ch * 32 + ct * 16 + lr) * KP + kb]);
        const s16x8 bf = __builtin_bit_cast(s16x8, bw);
        acc[ct] = __builtin_amdgcn_mfma_f32_16x16x32_bf16(af, bf, acc[ct], 0, 0, 0);
      }
    }

    unsigned short* st = st_s[wv_];
#pragma unroll
    for (int ct = 0; ct < 2; ++ct)
#pragma unroll
      for (int r = 0; r < 4; ++r)
        st[(lk * 4 + r) * 40 + ct * 16 + lr] = f2bf(acc[ct][r]);
    // wave-internal readback, transposed: lane -> (row l>>2, colq l&3)
    const int ri = l >> 2;
    const int grow = n0 + mt * 16 + ri;
    if (grow < NN) {
      const uint4 v = *reinterpret_cast<const uint4*>(&st[ri * 40 + (l & 3) * 8]);
      *reinterpret_cast<uint4*>(&Y2[(size_t)grow * NC + ch * 32 + (l & 3) * 8]) = v;
    }
  }
}

// ---------------- K3: gather-mean over Y2 [NN][64] bf16 -> fp32 out ---------
// 512 threads, 64 nodes/block; thread=(n = t>>3, l = t&7): 16B granule,
// 8 lanes cover the 128B row; v[16] batched loads.
__global__ __launch_bounds__(512) void gather_mean_out(
    const unsigned short* __restrict__ Y2, const int* __restrict__ idx,
    const float* __restrict__ w, float* __restrict__ out) {
  __shared__ int   idx_s[64][KNBR];
  __shared__ float w_s[64][KNBR];
  const int t  = threadIdx.x;
  const int n0 = blockIdx.x * 64;
#pragma unroll
  for (int j = 0; j < 2; ++j) {
    const int i = t + j * 512;
    const int node = i >> 4, k = i & 15;
    int gn = n0 + node; if (gn >= NN) gn = NN - 1;
    const int g = gn * (KNBR + 1) + 1 + k;
    idx_s[node][k] = idx[g];
    w_s[node][k]   = w[g];
  }
  __syncthreads();

  const int n = t >> 3, l = t & 7;
  const int gn = n0 + n;
  if (gn >= NN) return;
  const uint4* Y24 = reinterpret_cast<const uint4*>(Y2);  // row = 8 uint4
  uint4 v[KNBR];
#pragma unroll
  for (int k = 0; k < KNBR; ++k)
    v[k] = Y24[(size_t)idx_s[n][k] * 8 + l];
  float acc[8];
#pragma unroll
  for (int j = 0; j < 8; ++j) acc[j] = 0.f;
#pragma unroll
  for (int k = 0; k < KNBR; ++k) {
    const float wv = w_s[n][k];
    acc[0] += wv * bflo(v[k].x); acc[1] += wv * bfhi(v[k].x);
    acc[2] += wv * bflo(v[k].y); acc[3] += wv * bfhi(v[k].y);
    acc[4] += wv * bflo(v[k].z); acc[5] += wv * bfhi(v[k].z);
    acc[6] += wv * bflo(v[k].w); acc[7] += wv * bfhi(v[k].w);
  }
  float4* o4 = reinterpret_cast<float4*>(out);
  const size_t ob = ((size_t)gn * NC + l * 8) >> 2;
  o4[ob] = make_float4(acc[0] * (1.f / KNBR), acc[1] * (1.f / KNBR),
                       acc[2] * (1.f / KNBR), acc[3] * (1.f / KNBR));
  o4[ob + 1] = make_float4(acc[4] * (1.f / KNBR), acc[5] * (1.f / KNBR),
                           acc[6] * (1.f / KNBR), acc[7] * (1.f / KNBR));
}

extern "C" void kernel_launch(void* const* d_in, const int* in_sizes, int n_in,
                              void* d_out, int out_size, void* d_ws,
                              size_t ws_size, hipStream_t stream) {
  // 0:x 1:adj1_idx 2:adj1_w1(dead) 3:adj1_w2 4:adj2_idx 5:adj2_w1(dead)
  // 6:adj2_w2 7:W1 8:W2 9..18: relation params (ALL dead)
  const float* x   = (const float*)d_in[0];
  const int*   a1i = (const int*)d_in[1];
  const float* a1w = (const float*)d_in[3];
  const int*   a2i = (const int*)d_in[4];
  const float* a2w = (const float*)d_in[6];
  const float* W1  = (const float*)d_in[7];
  const float* W2  = (const float*)d_in[8];
  float*       out = (float*)d_out;

  unsigned short* Y1 = (unsigned short*)d_ws;    // [NN][128] bf16, 12.8 MB
  unsigned short* Y2 = Y1 + (size_t)NN * NF;     // [NN][64]  bf16,  6.4 MB

  gemm_mfma_128<<<(NN + 127) / 128, 256, 0, stream>>>(x, W1, Y1, NN);
  gather_gemm_fused<<<(NN + 63) / 64, 512, 0, stream>>>(Y1, a1i, a1w, W2, Y2);
  gather_mean_out<<<(NN + 63) / 64, 512, 0, stream>>>(Y2, a2i, a2w, out);
}